// Round 1
// baseline (130.591 us; speedup 1.0000x reference)
//
#include <hip/hip_runtime.h>

// AUAvULoss: probs[N,8], y[N,8] one-hot, weights[N,8] -> (avu_loss, CE_loss)
// Strategy:
//   init_k : zero 4x22 histogram, set umin/umax seeds, l0 = argmax(y[0,:8])
//            (faithful to reference bug: argmax over flattened y = label of row 0)
//   pass1_k: read probs+y+w, per-row entropy unc, focal/CE partial sums,
//            global umin/umax via uint atomics (unc >= 0)
//   pass2_k: re-read probs, recompute conf/pred/unc, bucket by first threshold
//            index t0 (22 bins, bin 21 = "no threshold satisfied"), LDS-staged
//            histogram of the 4 quadrant weights
//   final_k: prefix/suffix sums over bins -> avu[21] -> trapezoid AUC -> outputs

constexpr int C    = 8;
constexpr int NTH  = 21;
constexpr int NB   = 22;    // bins 0..20 = first threshold satisfied; 21 = none
constexpr int NBLK = 2048;
constexpr int BS   = 256;

struct Accum {
  unsigned umin_bits;
  unsigned umax_bits;
  int      l0;
  int      pad;
  float    hist[4][NB];        // 0=ac(le), 1=au(gt), 2=ic(le), 3=iu(gt)
  float    focal_part[NBLK];
  float    ce_part[NBLK];
};

__global__ __launch_bounds__(128) void init_k(Accum* acc, const float* __restrict__ y) {
  int t = threadIdx.x;
  if (t < 4 * NB) (&acc->hist[0][0])[t] = 0.f;
  if (t == 0) {
    acc->umin_bits = 0x7F800000u;  // +inf
    acc->umax_bits = 0u;           // 0.0f (entropy >= 0)
    float best = y[0]; int bi = 0;
#pragma unroll
    for (int j = 1; j < C; ++j) { if (y[j] > best) { best = y[j]; bi = j; } }
    acc->l0 = bi;
  }
}

__global__ __launch_bounds__(BS) void pass1_k(const float4* __restrict__ p4,
                                              const float4* __restrict__ y4,
                                              const float4* __restrict__ w4,
                                              Accum* acc, int N) {
  const float LOG_FEPS = -18.420680743952367f;  // logf(1e-8f)
  float fsum = 0.f, csum = 0.f;
  float umin = __uint_as_float(0x7F800000u), umax = 0.f;
  int stride = gridDim.x * blockDim.x;
  for (int i = blockIdx.x * blockDim.x + threadIdx.x; i < N; i += stride) {
    float4 a  = p4[2 * i], b  = p4[2 * i + 1];
    float4 ya = y4[2 * i], yb = y4[2 * i + 1];
    float4 wa = w4[2 * i], wb = w4[2 * i + 1];
    float p[8]  = {a.x, a.y, a.z, a.w, b.x, b.y, b.z, b.w};
    float yy[8] = {ya.x, ya.y, ya.z, ya.w, yb.x, yb.y, yb.z, yb.w};
    float ww[8] = {wa.x, wa.y, wa.z, wa.w, wb.x, wb.y, wb.z, wb.w};
    float unc = 0.f, ce = 0.f, fo = 0.f;
#pragma unroll
    for (int j = 0; j < 8; ++j) {
      float le = __logf(fmaxf(p[j], 1e-10f));   // entropy log (EPS=1e-10)
      unc -= p[j] * le;
      float lf = fmaxf(le, LOG_FEPS);           // = log(max(p,1e-8)), monotone log
      float t  = yy[j] * lf;
      ce -= t;
      fo -= t * ww[j];
    }
    fsum += fo; csum += ce;
    umin = fminf(umin, unc); umax = fmaxf(umax, unc);
  }
  // block reduce: 4 waves of 64
  float v0 = fsum, v1 = csum, v2 = umin, v3 = umax;
#pragma unroll
  for (int o = 32; o > 0; o >>= 1) {
    v0 += __shfl_down(v0, o);
    v1 += __shfl_down(v1, o);
    v2 = fminf(v2, __shfl_down(v2, o));
    v3 = fmaxf(v3, __shfl_down(v3, o));
  }
  __shared__ float r0[4], r1[4], r2[4], r3[4];
  int lane = threadIdx.x & 63, wid = threadIdx.x >> 6;
  if (lane == 0) { r0[wid] = v0; r1[wid] = v1; r2[wid] = v2; r3[wid] = v3; }
  __syncthreads();
  if (threadIdx.x == 0) {
    float f  = r0[0] + r0[1] + r0[2] + r0[3];
    float cc = r1[0] + r1[1] + r1[2] + r1[3];
    float mn = fminf(fminf(r2[0], r2[1]), fminf(r2[2], r2[3]));
    float mx = fmaxf(fmaxf(r3[0], r3[1]), fmaxf(r3[2], r3[3]));
    acc->focal_part[blockIdx.x] = f;
    acc->ce_part[blockIdx.x]    = cc;
    atomicMin(&acc->umin_bits, __float_as_uint(mn));  // unc >= 0: uint order == float order
    atomicMax(&acc->umax_bits, __float_as_uint(mx));
  }
}

__global__ __launch_bounds__(BS) void pass2_k(const float4* __restrict__ p4,
                                              Accum* acc, int N) {
  __shared__ float h[4][NB];
  for (int k = threadIdx.x; k < 4 * NB; k += BS) (&h[0][0])[k] = 0.f;
  __syncthreads();
  const float umin  = __uint_as_float(acc->umin_bits);
  const float umax  = __uint_as_float(acc->umax_bits);
  const int   l0    = acc->l0;
  const float scale = umax - umin;
  int stride = gridDim.x * blockDim.x;
  for (int i = blockIdx.x * blockDim.x + threadIdx.x; i < N; i += stride) {
    float4 a = p4[2 * i], b = p4[2 * i + 1];
    float p[8] = {a.x, a.y, a.z, a.w, b.x, b.y, b.z, b.w};
    float conf = p[0]; int pred = 0;
    float unc = 0.f;
#pragma unroll
    for (int j = 0; j < 8; ++j) {
      if (p[j] > conf) { conf = p[j]; pred = j; }   // first-occurrence argmax
      float le = __logf(fmaxf(p[j], 1e-10f));
      unc -= p[j] * le;
    }
    float tu = tanhf(unc);
    int t0 = NB - 1;  // "no threshold satisfied"
    for (int t = 0; t < NTH; ++t) {
      float thr = umin + ((float)t * 0.05f) * scale;   // same expr as reference
      if (unc <= thr) { t0 = t; break; }
    }
    bool  correct = (pred == l0);
    float base    = correct ? conf : (1.f - conf);
    int   row     = correct ? 0 : 2;
    atomicAdd(&h[row][t0],     base * (1.f - tu));
    atomicAdd(&h[row + 1][t0], base * tu);
  }
  __syncthreads();
  for (int k = threadIdx.x; k < 4 * NB; k += BS) {
    float v = (&h[0][0])[k];
    if (v != 0.f) atomicAdd(&acc->hist[0][0] + k, v);
  }
}

__global__ __launch_bounds__(BS) void final_k(Accum* acc, float* out, int N) {
  __shared__ double sf[BS], sc[BS];
  double f = 0.0, c = 0.0;
  for (int i = threadIdx.x; i < NBLK; i += BS) {
    f += (double)acc->focal_part[i];
    c += (double)acc->ce_part[i];
  }
  sf[threadIdx.x] = f; sc[threadIdx.x] = c;
  __syncthreads();
  for (int s = BS / 2; s > 0; s >>= 1) {
    if (threadIdx.x < s) { sf[threadIdx.x] += sf[threadIdx.x + s]; sc[threadIdx.x] += sc[threadIdx.x + s]; }
    __syncthreads();
  }
  if (threadIdx.x == 0) {
    float tot_au = 0.f, tot_iu = 0.f;
    for (int s = 0; s < NB; ++s) { tot_au += acc->hist[1][s]; tot_iu += acc->hist[3][s]; }
    float pac = 0.f, pau = 0.f, pic = 0.f, piu = 0.f, auc = 0.f, prev = 0.f;
    for (int t = 0; t < NTH; ++t) {
      pac += acc->hist[0][t]; pau += acc->hist[1][t];
      pic += acc->hist[2][t]; piu += acc->hist[3][t];
      float n_ac = pac, n_au = tot_au - pau, n_ic = pic, n_iu = tot_iu - piu;
      float avu = (n_ac + n_iu) / (n_ac + n_au + n_ic + n_iu + 1e-10f);
      if (t > 0) auc += 0.5f * (avu + prev) * 0.05f;
      prev = avu;
    }
    float focal_mean = (float)(sf[0] / (double)N);
    float ce_mean    = (float)(sc[0] / (double)N);
    out[0] = -logf(auc + 1e-10f) + focal_mean;   // BETA = 1
    out[1] = ce_mean;
  }
}

extern "C" void kernel_launch(void* const* d_in, const int* in_sizes, int n_in,
                              void* d_out, int out_size, void* d_ws, size_t ws_size,
                              hipStream_t stream) {
  const float* probs = (const float*)d_in[0];
  const float* y     = (const float*)d_in[1];
  const float* w     = (const float*)d_in[2];
  float* out = (float*)d_out;
  int N = in_sizes[0] / C;
  Accum* acc = (Accum*)d_ws;

  init_k<<<1, 128, 0, stream>>>(acc, y);
  pass1_k<<<NBLK, BS, 0, stream>>>((const float4*)probs, (const float4*)y,
                                   (const float4*)w, acc, N);
  pass2_k<<<NBLK, BS, 0, stream>>>((const float4*)probs, acc, N);
  final_k<<<1, BS, 0, stream>>>(acc, out, N);
}

// Round 2
// 58.203 us; speedup vs baseline: 2.2437x; 2.2437x over previous
//
#include <hip/hip_runtime.h>

// AUAvULoss: probs[N,8], y[N,8] one-hot, weights[N,8] -> (avu_loss, CE_loss)
//
// pass1_k : read probs+y+w (96 MB). Per sample: entropy unc, conf, pred,
//           focal/CE terms. Stash (unc, correct?conf:-conf) to ws (8 MB).
//           Per-block partials for focal/ce/umin/umax (NO global atomics).
// mid_k   : 1 block reduces the 2048 partials -> umin, umax, fsum, csum.
// pass2_k : read 8 MB stash. Bucket each sample by first threshold index t0
//           (bin 21 = none). LDS histogram replicated x32 (stride 89 ->
//           conflict-free replica banks, <=2-way atomic contention).
//           Flush as non-atomic per-block partial writes [88][NBLK2].
// final_k : reduce [88][NBLK2] partials, prefix/suffix sums -> avu[21] ->
//           trapezoid AUC -> out[0]=avu_loss, out[1]=CE.
// Fallback: if ws too small for the stash, pass2f_k re-reads probs.

constexpr int C     = 8;
constexpr int NTH   = 21;
constexpr int NB    = 22;     // 0..20 = first threshold satisfied; 21 = none
constexpr int NBLK1 = 2048;
constexpr int BS1   = 256;
constexpr int NBLK2 = 512;
constexpr int BS2   = 512;
constexpr int NREP  = 32;     // LDS histogram replicas
constexpr int RSTR  = 89;     // replica stride (odd -> replicas hit distinct banks)

struct Accum {
  int   l0;
  float umin, umax, fsum, csum;
  float f_part[NBLK1], c_part[NBLK1], mn_part[NBLK1], mx_part[NBLK1];
};

template <bool STASH>
__global__ __launch_bounds__(BS1) void pass1_k(const float4* __restrict__ p4,
                                               const float4* __restrict__ y4,
                                               const float4* __restrict__ w4,
                                               const float*  __restrict__ yraw,
                                               Accum* __restrict__ acc,
                                               float2* __restrict__ stash, int N) {
  __shared__ int sh_l0;
  if (threadIdx.x == 0) {
    float best = yraw[0]; int bi = 0;
#pragma unroll
    for (int j = 1; j < C; ++j) { if (yraw[j] > best) { best = yraw[j]; bi = j; } }
    sh_l0 = bi;
    if (blockIdx.x == 0) acc->l0 = bi;
  }
  __syncthreads();
  const int l0 = sh_l0;
  const float LOG_FEPS = -18.420680743952367f;  // logf(1e-8f)
  float fsum = 0.f, csum = 0.f;
  float umin = __uint_as_float(0x7F800000u), umax = 0.f;
  int stride = gridDim.x * blockDim.x;
  for (int i = blockIdx.x * blockDim.x + threadIdx.x; i < N; i += stride) {
    float4 a  = p4[2 * i], b  = p4[2 * i + 1];
    float4 ya = y4[2 * i], yb = y4[2 * i + 1];
    float4 wa = w4[2 * i], wb = w4[2 * i + 1];
    float p[8]  = {a.x, a.y, a.z, a.w, b.x, b.y, b.z, b.w};
    float yy[8] = {ya.x, ya.y, ya.z, ya.w, yb.x, yb.y, yb.z, yb.w};
    float ww[8] = {wa.x, wa.y, wa.z, wa.w, wb.x, wb.y, wb.z, wb.w};
    float unc = 0.f, ce = 0.f, fo = 0.f;
    float conf = p[0]; int pred = 0;
#pragma unroll
    for (int j = 0; j < 8; ++j) {
      if (p[j] > conf) { conf = p[j]; pred = j; }  // first-occurrence argmax
      float le = __logf(fmaxf(p[j], 1e-10f));      // entropy log (EPS=1e-10)
      unc -= p[j] * le;
      float lf = fmaxf(le, LOG_FEPS);              // = log(max(p,1e-8))
      float t  = yy[j] * lf;
      ce -= t;
      fo -= t * ww[j];
    }
    if (STASH) stash[i] = make_float2(unc, (pred == l0) ? conf : -conf);
    fsum += fo; csum += ce;
    umin = fminf(umin, unc); umax = fmaxf(umax, unc);
  }
  float v0 = fsum, v1 = csum, v2 = umin, v3 = umax;
#pragma unroll
  for (int o = 32; o > 0; o >>= 1) {
    v0 += __shfl_down(v0, o);
    v1 += __shfl_down(v1, o);
    v2 = fminf(v2, __shfl_down(v2, o));
    v3 = fmaxf(v3, __shfl_down(v3, o));
  }
  __shared__ float r0[4], r1[4], r2[4], r3[4];
  int lane = threadIdx.x & 63, wid = threadIdx.x >> 6;
  if (lane == 0) { r0[wid] = v0; r1[wid] = v1; r2[wid] = v2; r3[wid] = v3; }
  __syncthreads();
  if (threadIdx.x == 0) {
    acc->f_part[blockIdx.x]  = r0[0] + r0[1] + r0[2] + r0[3];
    acc->c_part[blockIdx.x]  = r1[0] + r1[1] + r1[2] + r1[3];
    acc->mn_part[blockIdx.x] = fminf(fminf(r2[0], r2[1]), fminf(r2[2], r2[3]));
    acc->mx_part[blockIdx.x] = fmaxf(fmaxf(r3[0], r3[1]), fmaxf(r3[2], r3[3]));
  }
}

__global__ __launch_bounds__(256) void mid_k(Accum* __restrict__ acc) {
  double f = 0.0, c = 0.0;
  float mn = __uint_as_float(0x7F800000u), mx = 0.f;
  for (int i = threadIdx.x; i < NBLK1; i += 256) {
    f += (double)acc->f_part[i];
    c += (double)acc->c_part[i];
    mn = fminf(mn, acc->mn_part[i]);
    mx = fmaxf(mx, acc->mx_part[i]);
  }
  __shared__ double sf[4], sc[4];
  __shared__ float smn[4], smx[4];
  int lane = threadIdx.x & 63, wid = threadIdx.x >> 6;
#pragma unroll
  for (int o = 32; o > 0; o >>= 1) {
    f += __shfl_down(f, o);
    c += __shfl_down(c, o);
    mn = fminf(mn, __shfl_down(mn, o));
    mx = fmaxf(mx, __shfl_down(mx, o));
  }
  if (lane == 0) { sf[wid] = f; sc[wid] = c; smn[wid] = mn; smx[wid] = mx; }
  __syncthreads();
  if (threadIdx.x == 0) {
    acc->fsum = (float)(sf[0] + sf[1] + sf[2] + sf[3]);
    acc->csum = (float)(sc[0] + sc[1] + sc[2] + sc[3]);
    acc->umin = fminf(fminf(smn[0], smn[1]), fminf(smn[2], smn[3]));
    acc->umax = fmaxf(fmaxf(smx[0], smx[1]), fmaxf(smx[2], smx[3]));
  }
}

__device__ __forceinline__ void hist_update(float* hb, float unc, float conf,
                                            bool correct, float umin, float scale) {
  float tu = tanhf(unc);
  int t0 = NB - 1;
  for (int t = 0; t < NTH; ++t) {
    float thr = umin + ((float)t * 0.05f) * scale;  // same expr as reference
    if (unc <= thr) { t0 = t; break; }
  }
  float base = correct ? conf : (1.f - conf);
  int   row  = correct ? 0 : 2;
  atomicAdd(&hb[row * NB + t0],       base * (1.f - tu));
  atomicAdd(&hb[(row + 1) * NB + t0], base * tu);
}

__global__ __launch_bounds__(BS2) void pass2_k(const float2* __restrict__ stash,
                                               const Accum* __restrict__ acc,
                                               float* __restrict__ partial2, int N) {
  __shared__ float h[NREP * RSTR];
  for (int k = threadIdx.x; k < NREP * RSTR; k += BS2) h[k] = 0.f;
  __syncthreads();
  const float umin  = acc->umin;
  const float scale = acc->umax - umin;
  float* hb = &h[(threadIdx.x & (NREP - 1)) * RSTR];
  int stride = gridDim.x * blockDim.x;
  for (int i = blockIdx.x * blockDim.x + threadIdx.x; i < N; i += stride) {
    float2 s = stash[i];
    hist_update(hb, s.x, fabsf(s.y), s.y > 0.f, umin, scale);
  }
  __syncthreads();
  for (int idx = threadIdx.x; idx < 4 * NB; idx += BS2) {
    float s = 0.f;
#pragma unroll
    for (int r = 0; r < NREP; ++r) s += h[r * RSTR + idx];
    partial2[idx * NBLK2 + blockIdx.x] = s;
  }
}

// Fallback: no stash space -> re-read probs, recompute conf/pred/unc.
__global__ __launch_bounds__(BS2) void pass2f_k(const float4* __restrict__ p4,
                                                const Accum* __restrict__ acc,
                                                float* __restrict__ partial2, int N) {
  __shared__ float h[NREP * RSTR];
  for (int k = threadIdx.x; k < NREP * RSTR; k += BS2) h[k] = 0.f;
  __syncthreads();
  const float umin  = acc->umin;
  const float scale = acc->umax - umin;
  const int   l0    = acc->l0;
  float* hb = &h[(threadIdx.x & (NREP - 1)) * RSTR];
  int stride = gridDim.x * blockDim.x;
  for (int i = blockIdx.x * blockDim.x + threadIdx.x; i < N; i += stride) {
    float4 a = p4[2 * i], b = p4[2 * i + 1];
    float p[8] = {a.x, a.y, a.z, a.w, b.x, b.y, b.z, b.w};
    float conf = p[0]; int pred = 0;
    float unc = 0.f;
#pragma unroll
    for (int j = 0; j < 8; ++j) {
      if (p[j] > conf) { conf = p[j]; pred = j; }
      unc -= p[j] * __logf(fmaxf(p[j], 1e-10f));
    }
    hist_update(hb, unc, conf, pred == l0, umin, scale);
  }
  __syncthreads();
  for (int idx = threadIdx.x; idx < 4 * NB; idx += BS2) {
    float s = 0.f;
#pragma unroll
    for (int r = 0; r < NREP; ++r) s += h[r * RSTR + idx];
    partial2[idx * NBLK2 + blockIdx.x] = s;
  }
}

__global__ __launch_bounds__(1024) void final_k(const float* __restrict__ partial2,
                                                const Accum* __restrict__ acc,
                                                float* __restrict__ out, int N) {
  __shared__ float hist[4 * NB];
  int lane = threadIdx.x & 63, wid = threadIdx.x >> 6;  // 16 waves
  for (int cidx = wid; cidx < 4 * NB; cidx += 16) {
    float s = 0.f;
    for (int k = lane; k < NBLK2; k += 64) s += partial2[cidx * NBLK2 + k];
#pragma unroll
    for (int o = 32; o > 0; o >>= 1) s += __shfl_down(s, o);
    if (lane == 0) hist[cidx] = s;
  }
  __syncthreads();
  if (threadIdx.x == 0) {
    const float* hac = &hist[0 * NB];
    const float* hau = &hist[1 * NB];
    const float* hic = &hist[2 * NB];
    const float* hiu = &hist[3 * NB];
    float tot_au = 0.f, tot_iu = 0.f;
    for (int s = 0; s < NB; ++s) { tot_au += hau[s]; tot_iu += hiu[s]; }
    float pac = 0.f, pau = 0.f, pic = 0.f, piu = 0.f, auc = 0.f, prev = 0.f;
    for (int t = 0; t < NTH; ++t) {
      pac += hac[t]; pau += hau[t]; pic += hic[t]; piu += hiu[t];
      float n_ac = pac, n_au = tot_au - pau, n_ic = pic, n_iu = tot_iu - piu;
      float avu = (n_ac + n_iu) / (n_ac + n_au + n_ic + n_iu + 1e-10f);
      if (t > 0) auc += 0.5f * (avu + prev) * 0.05f;
      prev = avu;
    }
    out[0] = -logf(auc + 1e-10f) + acc->fsum / (float)N;  // BETA = 1
    out[1] = acc->csum / (float)N;
  }
}

extern "C" void kernel_launch(void* const* d_in, const int* in_sizes, int n_in,
                              void* d_out, int out_size, void* d_ws, size_t ws_size,
                              hipStream_t stream) {
  const float* probs = (const float*)d_in[0];
  const float* y     = (const float*)d_in[1];
  const float* w     = (const float*)d_in[2];
  float* out = (float*)d_out;
  int N = in_sizes[0] / C;

  Accum* acc = (Accum*)d_ws;
  size_t off_p2 = (sizeof(Accum) + 255) & ~(size_t)255;
  size_t off_st = (off_p2 + (size_t)(4 * NB) * NBLK2 * sizeof(float) + 255) & ~(size_t)255;
  size_t need   = off_st + (size_t)N * sizeof(float2);
  float*  partial2 = (float*)((char*)d_ws + off_p2);
  float2* stash    = (float2*)((char*)d_ws + off_st);
  bool use_stash = (ws_size >= need);

  if (use_stash) {
    pass1_k<true><<<NBLK1, BS1, 0, stream>>>((const float4*)probs, (const float4*)y,
                                             (const float4*)w, y, acc, stash, N);
    mid_k<<<1, 256, 0, stream>>>(acc);
    pass2_k<<<NBLK2, BS2, 0, stream>>>(stash, acc, partial2, N);
  } else {
    pass1_k<false><<<NBLK1, BS1, 0, stream>>>((const float4*)probs, (const float4*)y,
                                              (const float4*)w, y, acc, nullptr, N);
    mid_k<<<1, 256, 0, stream>>>(acc);
    pass2f_k<<<NBLK2, BS2, 0, stream>>>((const float4*)probs, acc, partial2, N);
  }
  final_k<<<1, 1024, 0, stream>>>(partial2, acc, out, N);
}